// Round 1
// baseline (220.172 us; speedup 1.0000x reference)
//
#include <hip/hip_runtime.h>

#define CIN    128
#define HH     56
#define WW_    56
#define NBATCH 32
#define COUT   256
#define KTOT   1152          // 9 taps * 128 ci  (k-order: kh, kw, ci)
#define PLANE  3136          // 56*56
#define HP     58            // padded H/W
#define BM     256           // c_out tile = ALL of C_out (grid.y gone, xp read once)
#define BN     128           // pixel tile
#define NTILE  18            // K tiles of 64 ci: 9 taps * 2 halves

#define WB_OFF   0                         // bf16 weights [256][9][128] in ws
#define XP_OFF   (1u << 20)                // padded bf16 input [32][58][58][128]

#define ABUF_BYTES 32768                   // 256 rows * 128 B
#define BBUF_BYTES 16384                   // 128 rows * 128 B
#define BUF_STRIDE (ABUF_BYTES + BBUF_BYTES)
#define LDS_BYTES  (3 * BUF_STRIDE)        // tri-buffer: 147456 B <= 160 KiB

typedef __attribute__((ext_vector_type(8))) short bf16x8;
typedef __attribute__((ext_vector_type(4))) float f32x4;

__device__ __forceinline__ unsigned short f2bf(float f) {
    unsigned int u = __builtin_bit_cast(unsigned int, f);
    u += 0x7fffu + ((u >> 16) & 1u);   // RNE
    return (unsigned short)(u >> 16);
}

__device__ __forceinline__ void gl_lds16(const void* g, void* l) {
    __builtin_amdgcn_global_load_lds(
        (const __attribute__((address_space(1))) void*)g,
        (__attribute__((address_space(3))) void*)l, 16, 0, 0);
}

// ---- pre-pass 1: weights OIHW fp32 -> [o][tap][ci] bf16 ----
// v2: LDS transpose so global writes are coalesced uint4 (v1 did 1152
// scattered 2B stores/block -> ~16x write amplification at 32B granularity).
__global__ __launch_bounds__(256)
void wprep(const float* __restrict__ w, unsigned short* __restrict__ wb) {
    __shared__ __align__(16) unsigned short L[KTOT];
    const int o = blockIdx.x;
    const int t = threadIdx.x;
    const float4* src = (const float4*)(w + (size_t)o * KTOT);   // 288 float4
    #pragma unroll
    for (int e = 0; e < 2; ++e) {
        const int q = t + e * 256;
        if (q < 288) {
            const float4 v = src[q];
            #pragma unroll
            for (int u = 0; u < 4; ++u) {
                const int idx = q * 4 + u;       // = ci*9 + tap
                const int ci  = idx / 9;
                const int tap = idx - ci * 9;
                L[tap * 128 + ci] = f2bf(((const float*)&v)[u]);
            }
        }
    }
    __syncthreads();
    if (t < 144)                                  // 1152 shorts = 144 uint4
        ((uint4*)(wb + (size_t)o * KTOT))[t] = ((const uint4*)L)[t];
}

// ---- pre-pass 2: NCHW fp32 -> padded NHWC bf16 (unchanged, verified) ----
__global__ __launch_bounds__(256)
void xprep(const float* __restrict__ in, unsigned short* __restrict__ xp) {
    const int b  = blockIdx.x;               // n*58 + h_out
    const int n  = b / HP;
    const int ho = b - n * HP;
    const int t  = threadIdx.x;
    uint4* orow = (uint4*)(xp + (((size_t)n * HP + ho) * HP) * CIN);  // 928 uint4 per row

    if (ho == 0 || ho == HP - 1) {
        #pragma unroll
        for (int e = 0; e < 4; ++e) {
            const int idx = t + e * 256;
            if (idx < 928) orow[idx] = (uint4){0u, 0u, 0u, 0u};
        }
        return;
    }

    __shared__ unsigned short L[CIN * 57];   // [ci][w], padded to 57 shorts
    const int h  = ho - 1;
    const int w  = t & 63;
    const int cb = t >> 6;                   // wave id 0..3 -> ci block
    if (w < WW_) {
        const float* ib = in + ((size_t)n * CIN) * PLANE + (size_t)h * WW_ + w;
        #pragma unroll
        for (int e = 0; e < 32; ++e) {
            const int ci = cb * 32 + e;
            L[ci * 57 + w] = f2bf(ib[(size_t)ci * PLANE]);
        }
    }
    __syncthreads();

    #pragma unroll
    for (int e = 0; e < 4; ++e) {
        const int idx = t + e * 256;         // uint4 index within the row
        if (idx < 928) {
            const int wo = idx >> 4;         // pixel 0..57
            const int ch = idx & 15;         // 8-ci chunk
            uint4 pk = {0u, 0u, 0u, 0u};
            if (wo >= 1 && wo <= WW_) {
                const int wi = wo - 1;
                unsigned v[8];
                #pragma unroll
                for (int i = 0; i < 8; ++i)
                    v[i] = L[(ch * 8 + i) * 57 + wi];
                pk.x = v[0] | (v[1] << 16);
                pk.y = v[2] | (v[3] << 16);
                pk.z = v[4] | (v[5] << 16);
                pk.w = v[6] | (v[7] << 16);
            }
            orow[idx] = pk;
        }
    }
}

// ---- main: implicit-GEMM conv, 8-wave tri-buffered counted-vmcnt schedule ----
// A = wb[256][1152] (whole weight matrix per block), B = im2col rows.
// Per K-tile (64 ci): 2 phases (kk=0/1), each {8 ds_read_b128 | 3 gl_lds
// stage(kt+2) | s_barrier | lgkmcnt(0)+sched_barrier | setprio(1) 16 MFMA}.
// vmcnt(6) once per tile (6 loads of stage(kt+2) stay in flight) — never 0
// in steady state. Hazards: stage(kt+2) targets buf (kt+2)%3 != kt%3; the
// end-of-tile barrier separates last reads of a buffer from its restage.
__global__ __launch_bounds__(512, 2)
void conv_mfma(const unsigned short* __restrict__ wb,
               const unsigned short* __restrict__ xp,
               const float* __restrict__ bias,
               float* __restrict__ out)
{
    extern __shared__ __align__(16) char lds[];

    const int t    = threadIdx.x;
    const int pix0 = blockIdx.x * BN;

    const int slot = t & 7;
    const int r    = t >> 3;                 // 0..63
    const int swz  = (slot ^ (r & 7)) * 16;  // inverse-swizzled global source

    const char* aBase = (const char*)wb + (size_t)r * (KTOT * 2) + swz;
    const char* bBase[2];
    #pragma unroll
    for (int p = 0; p < 2; ++p) {
        const int pix = pix0 + r + p * 64;
        const int n   = pix / PLANE;
        const int rem = pix - n * PLANE;
        const int h   = rem / WW_;
        const int w   = rem - h * WW_;
        bBase[p] = (const char*)xp + ((size_t)(n * HP + h) * HP + w) * (CIN * 2) + swz;
    }

    const int lane = t & 63;
    const int wave = t >> 6;                 // 0..7: 4 M-groups x 2 N-groups
    const int wm   = (wave >> 1) * 64;
    const int wn   = (wave & 1) * 64;
    const int lr   = lane & 15;
    const int quad = lane >> 4;
    const int rmod = lr & 7;

    f32x4 acc[4][4];
    #pragma unroll
    for (int i = 0; i < 4; ++i)
        #pragma unroll
        for (int j = 0; j < 4; ++j)
            acc[i][j] = (f32x4){0.f, 0.f, 0.f, 0.f};

    auto stage = [&](int kt, int part) {     // 3 gl_lds per part, 6 per tile
        char* ab = lds + (kt % 3) * BUF_STRIDE;
        char* bb = ab + ABUF_BYTES;
        const int tap   = kt >> 1;
        const int ci0b  = (kt & 1) << 7;     // 0 or 128 bytes (64 ci half)
        const int abyte = tap * 256 + ci0b;
        const int toff  = ((tap / 3) * HP + (tap % 3)) * (CIN * 2) + ci0b;
        if (part == 0) {
            gl_lds16(aBase + (size_t)0 * 64 * (KTOT * 2) + abyte, ab + 0 * 8192 + t * 16);
            gl_lds16(aBase + (size_t)1 * 64 * (KTOT * 2) + abyte, ab + 1 * 8192 + t * 16);
            gl_lds16(bBase[0] + toff,                             bb + 0 * 8192 + t * 16);
        } else {
            gl_lds16(aBase + (size_t)2 * 64 * (KTOT * 2) + abyte, ab + 2 * 8192 + t * 16);
            gl_lds16(aBase + (size_t)3 * 64 * (KTOT * 2) + abyte, ab + 3 * 8192 + t * 16);
            gl_lds16(bBase[1] + toff,                             bb + 1 * 8192 + t * 16);
        }
    };

    // prologue: fill buf0 and buf1 (12 loads), wait only for buf0 (vmcnt 6)
    stage(0, 0); stage(0, 1);
    stage(1, 0); stage(1, 1);
    asm volatile("s_waitcnt vmcnt(6)" ::: "memory");
    __builtin_amdgcn_s_barrier();

    for (int kt = 0; kt < NTILE; ++kt) {
        const char* ab = lds + (kt % 3) * BUF_STRIDE;
        const char* bb = ab + ABUF_BYTES;
        bf16x8 af[4], bfr[4];

        // -------- phase A : kk = 0 --------
        {
            const int phys = (quad ^ rmod) * 16;
            #pragma unroll
            for (int i = 0; i < 4; ++i)
                af[i] = *(const bf16x8*)(ab + (wm + i * 16 + lr) * 128 + phys);
            #pragma unroll
            for (int j = 0; j < 4; ++j)
                bfr[j] = *(const bf16x8*)(bb + (wn + j * 16 + lr) * 128 + phys);
        }
        if (kt + 2 < NTILE) stage(kt + 2, 0);
        __builtin_amdgcn_s_barrier();
        asm volatile("s_waitcnt lgkmcnt(0)" ::: "memory");
        __builtin_amdgcn_sched_barrier(0);
        __builtin_amdgcn_s_setprio(1);
        #pragma unroll
        for (int i = 0; i < 4; ++i)
            #pragma unroll
            for (int j = 0; j < 4; ++j)
                acc[i][j] = __builtin_amdgcn_mfma_f32_16x16x32_bf16(af[i], bfr[j], acc[i][j], 0, 0, 0);
        __builtin_amdgcn_s_setprio(0);
        __builtin_amdgcn_s_barrier();

        // -------- phase B : kk = 1 --------
        {
            const int phys = ((4 + quad) ^ rmod) * 16;
            #pragma unroll
            for (int i = 0; i < 4; ++i)
                af[i] = *(const bf16x8*)(ab + (wm + i * 16 + lr) * 128 + phys);
            #pragma unroll
            for (int j = 0; j < 4; ++j)
                bfr[j] = *(const bf16x8*)(bb + (wn + j * 16 + lr) * 128 + phys);
        }
        if (kt + 2 < NTILE) stage(kt + 2, 1);
        __builtin_amdgcn_s_barrier();
        asm volatile("s_waitcnt lgkmcnt(0)" ::: "memory");
        __builtin_amdgcn_sched_barrier(0);
        __builtin_amdgcn_s_setprio(1);
        #pragma unroll
        for (int i = 0; i < 4; ++i)
            #pragma unroll
            for (int j = 0; j < 4; ++j)
                acc[i][j] = __builtin_amdgcn_mfma_f32_16x16x32_bf16(af[i], bfr[j], acc[i][j], 0, 0, 0);
        __builtin_amdgcn_s_setprio(0);
        // wait for stage(kt+1) before next tile reads it; stage(kt+2)'s 6
        // loads remain in flight (counted, not drained) except at the tail.
        if (kt + 2 < NTILE)      asm volatile("s_waitcnt vmcnt(6)" ::: "memory");
        else if (kt + 1 < NTILE) asm volatile("s_waitcnt vmcnt(0)" ::: "memory");
        __builtin_amdgcn_s_barrier();
    }

    #pragma unroll
    for (int j = 0; j < 4; ++j) {
        const int pg    = pix0 + wn + j * 16 + lr;
        const int ni    = pg / PLANE;
        const int inner = pg - ni * PLANE;
        float* op = out + (size_t)ni * (COUT * PLANE) + inner;
        #pragma unroll
        for (int i = 0; i < 4; ++i) {
            const int crow = wm + i * 16 + quad * 4;
            #pragma unroll
            for (int rr = 0; rr < 4; ++rr)
                op[(size_t)(crow + rr) * PLANE] = acc[i][j][rr] + bias[crow + rr];
        }
    }
}

extern "C" void kernel_launch(void* const* d_in, const int* in_sizes, int n_in,
                              void* d_out, int out_size, void* d_ws, size_t ws_size,
                              hipStream_t stream) {
    const float* in   = (const float*)d_in[0];
    const float* wt   = (const float*)d_in[1];
    const float* bias = (const float*)d_in[2];
    float* out        = (float*)d_out;

    unsigned short* wbuf = (unsigned short*)((char*)d_ws + WB_OFF);
    unsigned short* xpb  = (unsigned short*)((char*)d_ws + XP_OFF);

    // allow >64 KiB dynamic LDS (harmless if already permitted)
    (void)hipFuncSetAttribute((const void*)conv_mfma,
                              hipFuncAttributeMaxDynamicSharedMemorySize, LDS_BYTES);

    wprep<<<COUT, 256, 0, stream>>>(wt, wbuf);
    xprep<<<NBATCH * HP, 256, 0, stream>>>(in, xpb);

    conv_mfma<<<dim3((NBATCH * PLANE) / BN), 512, LDS_BYTES, stream>>>(wbuf, xpb, bias, out);
}

// Round 2
// 212.671 us; speedup vs baseline: 1.0353x; 1.0353x over previous
//
#include <hip/hip_runtime.h>

#define CIN    128
#define HH     56
#define WW_    56
#define NBATCH 32
#define COUT   256
#define KTOT   1152          // 9 taps * 128 ci  (k-order: kh, kw, ci)
#define PLANE  3136          // 56*56
#define HP     58            // padded H/W
#define BM     128           // c_out tile
#define BN     128           // pixel tile
#define NSTEP  36            // K steps of 32 ci: 9 taps * 4 quarters

#define WB_OFF   0                         // bf16 weights [256][9][128] in ws
#define XP_OFF   (1u << 20)                // padded bf16 input [32][58][58][128]

#define SLOT_BYTES 16384                   // A-half 8KB + B-half 8KB
#define LDS_BYTES  (4 * SLOT_BYTES)        // 64 KiB -> 2 blocks/CU

typedef __attribute__((ext_vector_type(8))) short bf16x8;
typedef __attribute__((ext_vector_type(4))) float f32x4;

__device__ __forceinline__ unsigned short f2bf(float f) {
    unsigned int u = __builtin_bit_cast(unsigned int, f);
    u += 0x7fffu + ((u >> 16) & 1u);   // RNE
    return (unsigned short)(u >> 16);
}

__device__ __forceinline__ void gl_lds16(const void* g, void* l) {
    __builtin_amdgcn_global_load_lds(
        (const __attribute__((address_space(1))) void*)g,
        (__attribute__((address_space(3))) void*)l, 16, 0, 0);
}

// ---- pre-pass 1: weights OIHW fp32 -> [o][tap][ci] bf16, coalesced out ----
__global__ __launch_bounds__(256)
void wprep(const float* __restrict__ w, unsigned short* __restrict__ wb) {
    __shared__ __align__(16) unsigned short L[KTOT];
    const int o = blockIdx.x;
    const int t = threadIdx.x;
    const float4* src = (const float4*)(w + (size_t)o * KTOT);   // 288 float4
    #pragma unroll
    for (int e = 0; e < 2; ++e) {
        const int q = t + e * 256;
        if (q < 288) {
            const float4 v = src[q];
            #pragma unroll
            for (int u = 0; u < 4; ++u) {
                const int idx = q * 4 + u;       // = ci*9 + tap
                const int ci  = idx / 9;
                const int tap = idx - ci * 9;
                L[tap * 128 + ci] = f2bf(((const float*)&v)[u]);
            }
        }
    }
    __syncthreads();
    if (t < 144)                                  // 1152 shorts = 144 uint4
        ((uint4*)(wb + (size_t)o * KTOT))[t] = ((const uint4*)L)[t];
}

// ---- pre-pass 2: NCHW fp32 -> padded NHWC bf16 (unchanged, verified) ----
__global__ __launch_bounds__(256)
void xprep(const float* __restrict__ in, unsigned short* __restrict__ xp) {
    const int b  = blockIdx.x;               // n*58 + h_out
    const int n  = b / HP;
    const int ho = b - n * HP;
    const int t  = threadIdx.x;
    uint4* orow = (uint4*)(xp + (((size_t)n * HP + ho) * HP) * CIN);  // 928 uint4 per row

    if (ho == 0 || ho == HP - 1) {
        #pragma unroll
        for (int e = 0; e < 4; ++e) {
            const int idx = t + e * 256;
            if (idx < 928) orow[idx] = (uint4){0u, 0u, 0u, 0u};
        }
        return;
    }

    __shared__ unsigned short L[CIN * 57];   // [ci][w], padded to 57 shorts
    const int h  = ho - 1;
    const int w  = t & 63;
    const int cb = t >> 6;                   // wave id 0..3 -> ci block
    if (w < WW_) {
        const float* ib = in + ((size_t)n * CIN) * PLANE + (size_t)h * WW_ + w;
        #pragma unroll
        for (int e = 0; e < 32; ++e) {
            const int ci = cb * 32 + e;
            L[ci * 57 + w] = f2bf(ib[(size_t)ci * PLANE]);
        }
    }
    __syncthreads();

    #pragma unroll
    for (int e = 0; e < 4; ++e) {
        const int idx = t + e * 256;         // uint4 index within the row
        if (idx < 928) {
            const int wo = idx >> 4;         // pixel 0..57
            const int ch = idx & 15;         // 8-ci chunk
            uint4 pk = {0u, 0u, 0u, 0u};
            if (wo >= 1 && wo <= WW_) {
                const int wi = wo - 1;
                unsigned v[8];
                #pragma unroll
                for (int i = 0; i < 8; ++i)
                    v[i] = L[(ch * 8 + i) * 57 + wi];
                pk.x = v[0] | (v[1] << 16);
                pk.y = v[2] | (v[3] << 16);
                pk.z = v[4] | (v[5] << 16);
                pk.w = v[6] | (v[7] << 16);
            }
            orow[idx] = pk;
        }
    }
}

// ---- main conv: 4-slot half-K pipeline, 1 barrier / 1 counted vmcnt per step,
// register loads pipelined one step ahead so lgkmcnt(0) is always pre-serviced.
// Slot layout: 64 lines x 128B; line L holds c-rows/pixels {2L,2L+1}, 8x16B
// slots, physical slot = logical ^ (L&7)  -> conflict-free ds_read_b128 AND
// linear gl_lds dest (source is pre-swizzled per-thread). ----
__global__ __launch_bounds__(256, 2)
void conv_mfma(const unsigned short* __restrict__ wb,
               const unsigned short* __restrict__ xp,
               const float* __restrict__ bias,
               float* __restrict__ out)
{
    extern __shared__ __align__(16) char lds[];

    const int t = threadIdx.x;

    // bijective XCD swizzle (1568 % 8 == 0): consecutive swizzled ids stay on
    // one XCD; pairs (2k,2k+1) share pix0 -> xp tile L2-resident per XCD.
    const int bid0 = blockIdx.x;
    const int bid  = (bid0 & 7) * ((NBATCH * PLANE / BN * 2) >> 3) + (bid0 >> 3);
    const int c0   = (bid & 1) * BM;
    const int pix0 = (bid >> 1) * BN;

    // ---- stage source/dest precompute (pre-swizzled global source) ----
    const char* aSrc[2]; const char* bSrc[2];
    int aDst[2], bDst[2];
    #pragma unroll
    for (int e = 0; e < 2; ++e) {
        const int idx  = t + e * 256;        // 16B unit within 8KB half
        const int line = idx >> 3;
        const int us   = (idx & 7) ^ (line & 7);   // unswizzled slot
        const int row  = 2 * line + (us >> 2);     // 0..127
        const int koff = (us & 3) * 16;            // 16B chunk within 64B row
        aSrc[e] = (const char*)wb + (size_t)(c0 + row) * (KTOT * 2) + koff;
        const int pix = pix0 + row;
        const int n   = pix / PLANE;
        const int rem = pix - n * PLANE;
        const int h   = rem / WW_;
        const int w   = rem - h * WW_;
        bSrc[e] = (const char*)xp + ((size_t)(n * HP + h) * HP + w) * (CIN * 2) + koff;
        aDst[e] = idx * 16;                  // linear LDS dest (gl_lds rule)
        bDst[e] = 8192 + idx * 16;
    }

    auto stage = [&](int hi) {               // 4 gl_lds -> slot hi&3
        char* slot = lds + (hi & 3) * SLOT_BYTES;
        const int tap  = hi >> 2;
        const int q    = hi & 3;
        const int aoff = tap * 256 + q * 64;
        const int boff = ((tap / 3) * HP + (tap % 3)) * (CIN * 2) + q * 64;
        gl_lds16(aSrc[0] + aoff, slot + aDst[0]);
        gl_lds16(aSrc[1] + aoff, slot + aDst[1]);
        gl_lds16(bSrc[0] + boff, slot + bDst[0]);
        gl_lds16(bSrc[1] + boff, slot + bDst[1]);
    };

    // ---- fragment read offsets (within a slot), swizzle-matched ----
    const int lane = t & 63;
    const int wave = t >> 6;
    const int wm   = (wave & 1) * 64;
    const int wn   = (wave >> 1) * 64;
    const int lr   = lane & 15;
    const int quad = lane >> 4;
    int offA[4], offB[4];
    #pragma unroll
    for (int i = 0; i < 4; ++i) {
        const int ra = wm + i * 16 + lr;
        offA[i] = (ra >> 1) * 128 + ((((ra & 1) * 4 + quad) ^ ((ra >> 1) & 7)) * 16);
        const int rb = wn + i * 16 + lr;
        offB[i] = 8192 + (rb >> 1) * 128 + ((((rb & 1) * 4 + quad) ^ ((rb >> 1) & 7)) * 16);
    }

    auto ldreg = [&](int hi, bf16x8 (&fr)[8]) {  // 8 ds_read_b128
        const char* slot = lds + (hi & 3) * SLOT_BYTES;
        #pragma unroll
        for (int i = 0; i < 4; ++i) fr[i]     = *(const bf16x8*)(slot + offA[i]);
        #pragma unroll
        for (int i = 0; i < 4; ++i) fr[4 + i] = *(const bf16x8*)(slot + offB[i]);
    };

    f32x4 acc[4][4];
    #pragma unroll
    for (int i = 0; i < 4; ++i)
        #pragma unroll
        for (int j = 0; j < 4; ++j)
            acc[i][j] = (f32x4){0.f, 0.f, 0.f, 0.f};

    auto domfma = [&](bf16x8 (&fr)[8]) {
        __builtin_amdgcn_s_setprio(1);
        #pragma unroll
        for (int i = 0; i < 4; ++i)
            #pragma unroll
            for (int j = 0; j < 4; ++j)
                acc[i][j] = __builtin_amdgcn_mfma_f32_16x16x32_bf16(fr[i], fr[4 + j], acc[i][j], 0, 0, 0);
        __builtin_amdgcn_s_setprio(0);
    };

    // steady-state step: {vmcnt(4): stage(hi+1) landed | barrier | lgkmcnt(0):
    // reads(hi) (issued LAST step) done | ds_read(hi+1) | stage(hi+3) | MFMA(hi)}
    auto step = [&](int hi, bf16x8 (&cur)[8], bf16x8 (&nxt)[8]) {
        asm volatile("s_waitcnt vmcnt(4)" ::: "memory");
        __builtin_amdgcn_s_barrier();
        asm volatile("s_waitcnt lgkmcnt(0)" ::: "memory");
        __builtin_amdgcn_sched_barrier(0);
        ldreg(hi + 1, nxt);
        if (hi + 3 < NSTEP) stage(hi + 3);
        domfma(cur);
    };

    // prologue: slots 0..2 staged; wait slot0 (8 left in flight), read step 0
    stage(0); stage(1); stage(2);
    asm volatile("s_waitcnt vmcnt(8)" ::: "memory");
    __builtin_amdgcn_s_barrier();

    bf16x8 fA[8], fB[8];
    ldreg(0, fA);

    for (int h2 = 0; h2 < NSTEP - 2; h2 += 2) {   // hi = 0..33, static ping-pong
        step(h2,     fA, fB);
        step(h2 + 1, fB, fA);
    }
    // hi = 34: last slot (35) must fully drain
    asm volatile("s_waitcnt vmcnt(0)" ::: "memory");
    __builtin_amdgcn_s_barrier();
    asm volatile("s_waitcnt lgkmcnt(0)" ::: "memory");
    __builtin_amdgcn_sched_barrier(0);
    ldreg(35, fB);
    domfma(fA);
    // hi = 35
    asm volatile("s_waitcnt lgkmcnt(0)" ::: "memory");
    __builtin_amdgcn_sched_barrier(0);
    domfma(fB);

    // ---- epilogue (identical layout to verified kernel) ----
    #pragma unroll
    for (int j = 0; j < 4; ++j) {
        const int pg    = pix0 + wn + j * 16 + lr;
        const int ni    = pg / PLANE;
        const int inner = pg - ni * PLANE;
        float* op = out + (size_t)ni * (COUT * PLANE) + inner;
        #pragma unroll
        for (int i = 0; i < 4; ++i) {
            const int crow = c0 + wm + i * 16 + quad * 4;
            #pragma unroll
            for (int r = 0; r < 4; ++r)
                op[(size_t)(crow + r) * PLANE] = acc[i][j][r] + bias[crow + r];
        }
    }
}

extern "C" void kernel_launch(void* const* d_in, const int* in_sizes, int n_in,
                              void* d_out, int out_size, void* d_ws, size_t ws_size,
                              hipStream_t stream) {
    const float* in   = (const float*)d_in[0];
    const float* wt   = (const float*)d_in[1];
    const float* bias = (const float*)d_in[2];
    float* out        = (float*)d_out;

    unsigned short* wbuf = (unsigned short*)((char*)d_ws + WB_OFF);
    unsigned short* xpb  = (unsigned short*)((char*)d_ws + XP_OFF);

    (void)hipFuncSetAttribute((const void*)conv_mfma,
                              hipFuncAttributeMaxDynamicSharedMemorySize, LDS_BYTES);

    wprep<<<COUT, 256, 0, stream>>>(wt, wbuf);
    xprep<<<NBATCH * HP, 256, 0, stream>>>(in, xpb);

    conv_mfma<<<dim3((NBATCH * PLANE / BN) * 2), 256, LDS_BYTES, stream>>>(wbuf, xpb, bias, out);
}